// Round 10
// baseline (183.553 us; speedup 1.0000x reference)
//
#include <hip/hip_runtime.h>
#include <hip/hip_bf16.h>
#include <math.h>

#define SA_N 2048
#define SA_D 1024
#define SA_H 16
#define SA_HD 64

typedef __attribute__((ext_vector_type(8))) short bf16x8;
typedef __attribute__((ext_vector_type(4))) float f32x4;
typedef __attribute__((address_space(3))) void lds_t;
typedef __attribute__((address_space(1))) void gmem_t;

#define SC2 0.18033688011112042f   // (1/sqrt(64)) * log2(e), folded into Wq/bq

// ---------------- merged prep: x->bf16 and 4x W[K][N] -> bf16 Wt[N][K] ----------------
__global__ __launch_bounds__(256) void prep_kernel(
    const float* __restrict__ x,
    const float* __restrict__ Wq, const float* __restrict__ Wk,
    const float* __restrict__ Wv, const float* __restrict__ Wo,
    __hip_bfloat16* __restrict__ xbf, __hip_bfloat16* __restrict__ WtAll)
{
    const int tid = threadIdx.x;
    const int z = blockIdx.z;
    if (z < 2) {
        const int r = z * 1024 + blockIdx.y * 32 + (tid >> 3);
        const int c = blockIdx.x * 32 + (tid & 7) * 4;
        const size_t idx = (size_t)r * SA_D + c;
        float4 v = *reinterpret_cast<const float4*>(&x[idx]);
        union { __hip_bfloat16 hh[4]; short4 s4; } u;
        u.hh[0] = __float2bfloat16(v.x);
        u.hh[1] = __float2bfloat16(v.y);
        u.hh[2] = __float2bfloat16(v.z);
        u.hh[3] = __float2bfloat16(v.w);
        *reinterpret_cast<short4*>(&xbf[idx]) = u.s4;
    } else {
        const int w = z - 2;
        const float* W = (w == 0) ? Wq : (w == 1) ? Wk : (w == 2) ? Wv : Wo;
        const float scale = (w == 0) ? SC2 : 1.0f;
        __hip_bfloat16* Wt = WtAll + (size_t)w * SA_D * SA_D;
        __shared__ float t[32][33];
        const int c0 = blockIdx.x * 32, r0 = blockIdx.y * 32;
        const int tx = tid & 31, ty = tid >> 5;
#pragma unroll
        for (int p = 0; p < 4; ++p)
            t[ty + p * 8][tx] = W[(size_t)(r0 + ty + p * 8) * SA_D + c0 + tx] * scale;
        __syncthreads();
#pragma unroll
        for (int p = 0; p < 4; ++p)
            Wt[(size_t)(c0 + ty + p * 8) * SA_D + r0 + tx] =
                __float2bfloat16(t[tx][ty + p * 8]);
    }
}

// ---------------- bf16 MFMA GEMM 64x64 tile body, v2 ----------------
// B-fragments read DIRECTLY from global (L2-hot weights) into registers; only A
// is staged in LDS (global_load_lds + XOR swizzle). LDS reads per k-iter per
// wave: 8 -> 4 b128 (balanced vs 8 MFMA). B loads issue before the barrier, so
// the barrier's vmcnt(0) drain covers them — free pipelining. LDS/block 8 KB.
// mode 0: fp32 C natural; mode 1: bf16 C natural; mode 2: bf16 C transposed [N][M].
__device__ __forceinline__ void gemm_tile_body(
    const __hip_bfloat16* __restrict__ A,
    const __hip_bfloat16* __restrict__ Bt,
    const float* __restrict__ bias, float bias_scale,
    void* __restrict__ Cout, int mode, int M, int Kdim, int Nout,
    char* As)
{
    const int tid = threadIdx.x;
    const int wave = tid >> 6, lane = tid & 63;
    const int m = lane & 15, quad = lane >> 4;
    const int wm = wave >> 1, wn = wave & 1;
    const int row0 = blockIdx.y * 64, col0 = blockIdx.x * 64;

    f32x4 acc[2][2];
#pragma unroll
    for (int i = 0; i < 2; ++i)
#pragma unroll
        for (int j = 0; j < 2; ++j) acc[i][j] = (f32x4){0.f, 0.f, 0.f, 0.f};

    const int sr = tid >> 3;
    const int sc = tid & 7;

    // per-lane B row pointers (col fixed per ni)
    const __hip_bfloat16* brow[2];
#pragma unroll
    for (int ni = 0; ni < 2; ++ni)
        brow[ni] = Bt + (size_t)(col0 + wn * 32 + ni * 16 + m) * Kdim + quad * 8;

    for (int k0 = 0; k0 < Kdim; k0 += 64) {
        // B-fragments for this k0: 4x global dwordx4 (L2-hot), issued pre-barrier
        bf16x8 bfr[2][2];
#pragma unroll
        for (int s = 0; s < 2; ++s)
#pragma unroll
            for (int ni = 0; ni < 2; ++ni)
                bfr[s][ni] = *reinterpret_cast<const bf16x8*>(brow[ni] + k0 + s * 32);

        // A staging: 64 rows x 8 chunks, 2 rounds
#pragma unroll
        for (int p = 0; p < 2; ++p) {
            const int r = p * 32 + sr;
            const int pc = (sc ^ (r & 7)) * 16;
            const char* ga = (const char*)(A + (size_t)(row0 + r) * Kdim + k0) + pc;
            __builtin_amdgcn_global_load_lds((gmem_t*)ga,
                (lds_t*)(As + p * 4096 + wave * 1024), 16, 0, 0);
        }
        __syncthreads();   // drains vmcnt(0): A in LDS, B in regs

#pragma unroll
        for (int s = 0; s < 2; ++s) {
            bf16x8 af[2];
#pragma unroll
            for (int mi = 0; mi < 2; ++mi) {
                const int row = wm * 32 + mi * 16 + m;
                const int pc = (s * 4 + quad) ^ (row & 7);
                af[mi] = *reinterpret_cast<const bf16x8*>(As + row * 128 + pc * 16);
            }
#pragma unroll
            for (int mi = 0; mi < 2; ++mi)
#pragma unroll
                for (int ni = 0; ni < 2; ++ni)
                    acc[mi][ni] = __builtin_amdgcn_mfma_f32_16x16x32_bf16(
                        af[mi], bfr[s][ni], acc[mi][ni], 0, 0, 0);
        }
        __syncthreads();
    }

#pragma unroll
    for (int ni = 0; ni < 2; ++ni) {
        const int col = col0 + wn * 32 + ni * 16 + m;
        const float bv = bias[col] * bias_scale;
#pragma unroll
        for (int mi = 0; mi < 2; ++mi) {
            const int rbase = row0 + wm * 32 + mi * 16 + quad * 4;
            if (mode == 0) {
#pragma unroll
                for (int reg = 0; reg < 4; ++reg)
                    ((float*)Cout)[(size_t)(rbase + reg) * Nout + col] =
                        acc[mi][ni][reg] + bv;
            } else if (mode == 1) {
#pragma unroll
                for (int reg = 0; reg < 4; ++reg)
                    ((__hip_bfloat16*)Cout)[(size_t)(rbase + reg) * Nout + col] =
                        __float2bfloat16(acc[mi][ni][reg] + bv);
            } else {
                union { __hip_bfloat16 hh[4]; short4 s4; } u;
#pragma unroll
                for (int reg = 0; reg < 4; ++reg)
                    u.hh[reg] = __float2bfloat16(acc[mi][ni][reg] + bv);
                *reinterpret_cast<short4*>(
                    &((__hip_bfloat16*)Cout)[(size_t)col * M + rbase]) = u.s4;
            }
        }
    }
}

__global__ __launch_bounds__(256) void gemm_qkv_kernel(
    const __hip_bfloat16* __restrict__ xbf, const __hip_bfloat16* __restrict__ WtAll,
    const float* __restrict__ bq, const float* __restrict__ bk, const float* __restrict__ bv,
    __hip_bfloat16* __restrict__ Qb, __hip_bfloat16* __restrict__ Kb,
    __hip_bfloat16* __restrict__ VtT)
{
    __shared__ __align__(16) char As[64 * 128];
    const int z = blockIdx.z;
    const __hip_bfloat16* Bt = WtAll + (size_t)z * SA_D * SA_D;
    const float* bias = (z == 0) ? bq : (z == 1) ? bk : bv;
    void* out = (z == 0) ? (void*)Qb : (z == 1) ? (void*)Kb : (void*)VtT;
    gemm_tile_body(xbf, Bt, bias, (z == 0) ? SC2 : 1.0f, out,
                   (z == 2) ? 2 : 1, SA_N, SA_D, SA_D, As);
}

__global__ __launch_bounds__(256) void gemm_out_kernel(
    const __hip_bfloat16* __restrict__ Abf, const __hip_bfloat16* __restrict__ Wt,
    const float* __restrict__ bo, float* __restrict__ out)
{
    __shared__ __align__(16) char As[64 * 128];
    gemm_tile_body(Abf, Wt, bo, 1.0f, out, 0, SA_N, SA_D, SA_D, As);
}

// ---------------- MFMA flash attention v5b: split-K groups + Q in registers ----------------
// R9's v5 with launch_bounds relaxed to (512,4): the (512,6) VGPR cap (84) cost
// more than the 3rd block gained. LDS 50.25 KB; 2-3 blocks/CU as VGPRs allow.
__global__ __launch_bounds__(512, 4) void flash_mfma_kernel(
    const __hip_bfloat16* __restrict__ Qb,  // [N][D], pre-scaled by SC2
    const __hip_bfloat16* __restrict__ Kb,  // [N][D]
    const __hip_bfloat16* __restrict__ Vt,  // [D][N]
    __hip_bfloat16* __restrict__ O)         // [N][D]
{
    const int b = blockIdx.x;
    const int h = b & 15;
    const int qraw = b >> 4;
    const int qt = (qraw < 16) ? qraw : 47 - qraw;  // fold for CU balance
    const int row0 = qt * 64;
    const int ntiles = (qt >> 1) + 1;               // 128-key tiles

    const int tid = threadIdx.x;
    const int wave = tid >> 6, lane = tid & 63;
    const int g = wave >> 2, w4 = wave & 3;         // group, wave-in-group
    const int ln = lane & 15, quad = lane >> 4;

    __shared__ __align__(16) char Ks[128 * 128];    // [key][dim] bf16 (reused as fp32 merge buf)
    __shared__ __align__(16) char Vs[64 * 256];     // [dim][key] bf16, 128 keys/row
    __shared__ __align__(16) char Ps[2][64 * 144];  // per-group [qrow][key] bf16
    __shared__ float lmerge[64];

    // Q A-fragments directly to registers (one-time, L2-hot)
    bf16x8 qf[2];
#pragma unroll
    for (int s = 0; s < 2; ++s)
        qf[s] = *reinterpret_cast<const bf16x8*>(
            Qb + (size_t)(row0 + w4 * 16 + ln) * SA_D + h * SA_HD + s * 32 + quad * 8);

    f32x4 oacc[4], lacc;
#pragma unroll
    for (int dg = 0; dg < 4; ++dg) oacc[dg] = (f32x4){0.f, 0.f, 0.f, 0.f};
    lacc = (f32x4){0.f, 0.f, 0.f, 0.f};

    const short one_bf = (short)0x3F80;
    const bf16x8 ones = {one_bf, one_bf, one_bf, one_bf, one_bf, one_bf, one_bf, one_bf};

    for (int kt = 0; kt < ntiles; ++kt) {
        __syncthreads();   // all waves done reading Ks/Vs from prev iter
#pragma unroll
        for (int p = 0; p < 2; ++p) {
            const int r = p * 64 + wave * 8 + (lane >> 3);
            const int pc = ((lane & 7) ^ (r & 7)) * 16;
            const char* gk = (const char*)(Kb + (size_t)(kt * 128 + r) * SA_D + h * SA_HD) + pc;
            __builtin_amdgcn_global_load_lds((gmem_t*)gk,
                (lds_t*)(Ks + p * 8192 + wave * 1024), 16, 0, 0);
        }
#pragma unroll
        for (int p = 0; p < 2; ++p) {
            const int r = p * 32 + wave * 4 + (lane >> 4);
            const int pc = ((lane & 15) ^ (r & 15)) * 16;
            const char* gv = (const char*)(Vt + (size_t)(h * SA_HD + r) * SA_N + kt * 128) + pc;
            __builtin_amdgcn_global_load_lds((gmem_t*)gv,
                (lds_t*)(Vs + p * 8192 + wave * 1024), 16, 0, 0);
        }
        __syncthreads();   // staged data visible (vmcnt drained at barrier)

        // S = Q K^T : wave's 16 q-rows x group's 64 keys
        f32x4 sacc[4];
#pragma unroll
        for (int gg = 0; gg < 4; ++gg) sacc[gg] = (f32x4){0.f, 0.f, 0.f, 0.f};
#pragma unroll
        for (int s = 0; s < 2; ++s) {
#pragma unroll
            for (int gg = 0; gg < 4; ++gg) {
                const int krow = g * 64 + gg * 16 + ln;
                const int pcb = (s * 4 + quad) ^ (krow & 7);
                bf16x8 bf = *reinterpret_cast<const bf16x8*>(Ks + krow * 128 + pcb * 16);
                sacc[gg] = __builtin_amdgcn_mfma_f32_16x16x32_bf16(qf[s], bf, sacc[gg], 0, 0, 0);
            }
        }

        // P = exp2(S) + causal mask (only last tile straddles/exceeds diagonal)
        const bool last = (kt == ntiles - 1);
        const int prow_b = w4 * 16 + quad * 4;
        const int qrow_b = row0 + prow_b;
        char* Pg = Ps[g];
#pragma unroll
        for (int gg = 0; gg < 4; ++gg) {
            const int key = kt * 128 + g * 64 + gg * 16 + ln;
#pragma unroll
            for (int reg = 0; reg < 4; ++reg) {
                float p = exp2f(sacc[gg][reg]);
                if (last && key > (qrow_b + reg)) p = 0.f;
                *reinterpret_cast<__hip_bfloat16*>(
                    Pg + (prow_b + reg) * 144 + (gg * 16 + ln) * 2) = __float2bfloat16(p);
            }
        }

        // O += P V ; l += P . ones   (V columns of this group's keys)
#pragma unroll
        for (int s2 = 0; s2 < 2; ++s2) {
            bf16x8 pf = *reinterpret_cast<const bf16x8*>(
                Pg + (w4 * 16 + ln) * 144 + s2 * 64 + quad * 16);
            lacc = __builtin_amdgcn_mfma_f32_16x16x32_bf16(pf, ones, lacc, 0, 0, 0);
#pragma unroll
            for (int dg = 0; dg < 4; ++dg) {
                const int vrow = dg * 16 + ln;
                const int kc = g * 8 + s2 * 4 + quad;       // key-chunk within 128-key row
                const int pcb = (kc ^ (vrow & 15)) * 16;
                bf16x8 vf = *reinterpret_cast<const bf16x8*>(Vs + vrow * 256 + pcb);
                oacc[dg] = __builtin_amdgcn_mfma_f32_16x16x32_bf16(pf, vf, oacc[dg], 0, 0, 0);
            }
        }
    }

    // merge groups: group 1 dumps fp32 partials into Ks (16 KB = 64x64 f32)
    __syncthreads();
    float* Kf = reinterpret_cast<float*>(Ks);
    if (g == 1) {
#pragma unroll
        for (int reg = 0; reg < 4; ++reg) {
            const int row = w4 * 16 + quad * 4 + reg;
#pragma unroll
            for (int dg = 0; dg < 4; ++dg)
                Kf[row * 64 + dg * 16 + ln] = oacc[dg][reg];
            if (ln == 0) lmerge[row] = lacc[reg];
        }
    }
    __syncthreads();
    if (g == 0) {
#pragma unroll
        for (int reg = 0; reg < 4; ++reg) {
            const int row = w4 * 16 + quad * 4 + reg;
            const float inv = 1.0f / (lacc[reg] + lmerge[row]);
            const int qrow = row0 + row;
#pragma unroll
            for (int dg = 0; dg < 4; ++dg)
                O[(size_t)qrow * SA_D + h * SA_HD + dg * 16 + ln] =
                    __float2bfloat16((oacc[dg][reg] + Kf[row * 64 + dg * 16 + ln]) * inv);
        }
    }
}

extern "C" void kernel_launch(void* const* d_in, const int* in_sizes, int n_in,
                              void* d_out, int out_size, void* d_ws, size_t ws_size,
                              hipStream_t stream) {
    const float* x  = (const float*)d_in[0];
    const float* Wq = (const float*)d_in[1];
    const float* bq = (const float*)d_in[2];
    const float* Wk = (const float*)d_in[3];
    const float* bk = (const float*)d_in[4];
    const float* Wv = (const float*)d_in[5];
    const float* bv = (const float*)d_in[6];
    const float* Wo = (const float*)d_in[7];
    const float* bo = (const float*)d_in[8];
    float* out = (float*)d_out;

    const size_t ND = (size_t)SA_N * SA_D;
    const size_t DD = (size_t)SA_D * SA_D;
    __hip_bfloat16* xbf   = (__hip_bfloat16*)d_ws;
    __hip_bfloat16* WtAll = xbf + ND;
    __hip_bfloat16* Qb    = WtAll + 4 * DD;
    __hip_bfloat16* Kb    = Qb + ND;
    __hip_bfloat16* VtT   = Kb + ND;
    __hip_bfloat16* Abf   = VtT + ND;

    prep_kernel<<<dim3(32, 32, 6), 256, 0, stream>>>(x, Wq, Wk, Wv, Wo, xbf, WtAll);
    gemm_qkv_kernel<<<dim3(SA_D / 64, SA_N / 64, 3), 256, 0, stream>>>(
        xbf, WtAll, bq, bk, bv, Qb, Kb, VtT);
    flash_mfma_kernel<<<dim3(512), 512, 0, stream>>>(Qb, Kb, VtT, Abf);
    gemm_out_kernel<<<dim3(SA_D / 64, SA_N / 64), 256, 0, stream>>>(
        Abf, WtAll + 3 * DD, bo, out);
}

// Round 11
// 144.076 us; speedup vs baseline: 1.2740x; 1.2740x over previous
//
#include <hip/hip_runtime.h>
#include <hip/hip_bf16.h>
#include <math.h>

#define SA_N 2048
#define SA_D 1024
#define SA_H 16
#define SA_HD 64

typedef __attribute__((ext_vector_type(8))) short bf16x8;
typedef __attribute__((ext_vector_type(4))) float f32x4;
typedef __attribute__((address_space(3))) void lds_t;
typedef __attribute__((address_space(1))) void gmem_t;

#define SC2 0.18033688011112042f   // (1/sqrt(64)) * log2(e), folded into Wq/bq

// ---------------- merged prep: x->bf16 and 4x W[K][N] -> bf16 Wt[N][K] ----------------
__global__ __launch_bounds__(256) void prep_kernel(
    const float* __restrict__ x,
    const float* __restrict__ Wq, const float* __restrict__ Wk,
    const float* __restrict__ Wv, const float* __restrict__ Wo,
    __hip_bfloat16* __restrict__ xbf, __hip_bfloat16* __restrict__ WtAll)
{
    const int tid = threadIdx.x;
    const int z = blockIdx.z;
    if (z < 2) {
        const int r = z * 1024 + blockIdx.y * 32 + (tid >> 3);
        const int c = blockIdx.x * 32 + (tid & 7) * 4;
        const size_t idx = (size_t)r * SA_D + c;
        float4 v = *reinterpret_cast<const float4*>(&x[idx]);
        union { __hip_bfloat16 hh[4]; short4 s4; } u;
        u.hh[0] = __float2bfloat16(v.x);
        u.hh[1] = __float2bfloat16(v.y);
        u.hh[2] = __float2bfloat16(v.z);
        u.hh[3] = __float2bfloat16(v.w);
        *reinterpret_cast<short4*>(&xbf[idx]) = u.s4;
    } else {
        const int w = z - 2;
        const float* W = (w == 0) ? Wq : (w == 1) ? Wk : (w == 2) ? Wv : Wo;
        const float scale = (w == 0) ? SC2 : 1.0f;
        __hip_bfloat16* Wt = WtAll + (size_t)w * SA_D * SA_D;
        __shared__ float t[32][33];
        const int c0 = blockIdx.x * 32, r0 = blockIdx.y * 32;
        const int tx = tid & 31, ty = tid >> 5;
#pragma unroll
        for (int p = 0; p < 4; ++p)
            t[ty + p * 8][tx] = W[(size_t)(r0 + ty + p * 8) * SA_D + c0 + tx] * scale;
        __syncthreads();
#pragma unroll
        for (int p = 0; p < 4; ++p)
            Wt[(size_t)(c0 + ty + p * 8) * SA_D + r0 + tx] =
                __float2bfloat16(t[tx][ty + p * 8]);
    }
}

// ---------------- fused QKV GEMM: one block computes Q,K,V tiles sharing A ----------------
// Block tile 64 rows x 32 cols, BK=64. Per k-iter: stage A (2 rounds) + 3 B-tiles
// (1 round each) via global_load_lds + XOR swizzle; 12 MFMA/wave vs 5 staging
// rounds (R8 split kernels: 8 vs 4, and A fetched 3x). Grid 32x32 = 1024 blocks
// = 4/CU. LDS 8K + 3x4K = 20 KB. R10 lesson: B stays on the LDS path.
__global__ __launch_bounds__(256) void gemm_qkv_kernel(
    const __hip_bfloat16* __restrict__ xbf, const __hip_bfloat16* __restrict__ WtAll,
    const float* __restrict__ bq, const float* __restrict__ bk, const float* __restrict__ bv,
    __hip_bfloat16* __restrict__ Qb, __hip_bfloat16* __restrict__ Kb,
    __hip_bfloat16* __restrict__ VtT)
{
    __shared__ __align__(16) char As[64 * 128];
    __shared__ __align__(16) char Bs[3][32 * 128];

    const int tid = threadIdx.x;
    const int wave = tid >> 6, lane = tid & 63;
    const int m = lane & 15, quad = lane >> 4;
    const int wm = wave >> 1, wn = wave & 1;
    const int row0 = blockIdx.y * 64, col0 = blockIdx.x * 32;

    f32x4 acc[3][2];
#pragma unroll
    for (int w = 0; w < 3; ++w)
#pragma unroll
        for (int mi = 0; mi < 2; ++mi) acc[w][mi] = (f32x4){0.f, 0.f, 0.f, 0.f};

    const int sr = tid >> 3;   // 0..31
    const int sc = tid & 7;    // chunk

    for (int k0 = 0; k0 < SA_D; k0 += 64) {
        // A: 64 rows, 2 rounds of 32
#pragma unroll
        for (int p = 0; p < 2; ++p) {
            const int r = p * 32 + sr;
            const int pc = (sc ^ (r & 7)) * 16;
            const char* ga = (const char*)(xbf + (size_t)(row0 + r) * SA_D + k0) + pc;
            __builtin_amdgcn_global_load_lds((gmem_t*)ga,
                (lds_t*)(As + p * 4096 + wave * 1024), 16, 0, 0);
        }
        // B (x3): 32 rows each, 1 round
#pragma unroll
        for (int w = 0; w < 3; ++w) {
            const int pc = (sc ^ (sr & 7)) * 16;
            const char* gb = (const char*)(WtAll + (size_t)w * SA_D * SA_D
                                           + (size_t)(col0 + sr) * SA_D + k0) + pc;
            __builtin_amdgcn_global_load_lds((gmem_t*)gb,
                (lds_t*)(Bs[w] + wave * 1024), 16, 0, 0);
        }
        __syncthreads();

#pragma unroll
        for (int s = 0; s < 2; ++s) {
            bf16x8 af[2];
#pragma unroll
            for (int mi = 0; mi < 2; ++mi) {
                const int row = wm * 32 + mi * 16 + m;
                const int pc = (s * 4 + quad) ^ (row & 7);
                af[mi] = *reinterpret_cast<const bf16x8*>(As + row * 128 + pc * 16);
            }
            const int rb = wn * 16 + m;
            const int pcb = (s * 4 + quad) ^ (rb & 7);
#pragma unroll
            for (int w = 0; w < 3; ++w) {
                bf16x8 bf = *reinterpret_cast<const bf16x8*>(Bs[w] + rb * 128 + pcb * 16);
#pragma unroll
                for (int mi = 0; mi < 2; ++mi)
                    acc[w][mi] = __builtin_amdgcn_mfma_f32_16x16x32_bf16(
                        af[mi], bf, acc[w][mi], 0, 0, 0);
            }
        }
        __syncthreads();
    }

    // epilogue: Q,K natural bf16; V transposed [N][M] bf16
    const int col = col0 + wn * 16 + m;
    const float bvq = bq[col] * SC2, bvk = bk[col], bvv = bv[col];
#pragma unroll
    for (int mi = 0; mi < 2; ++mi) {
        const int rbase = row0 + wm * 32 + mi * 16 + quad * 4;
#pragma unroll
        for (int reg = 0; reg < 4; ++reg) {
            Qb[(size_t)(rbase + reg) * SA_D + col] = __float2bfloat16(acc[0][mi][reg] + bvq);
            Kb[(size_t)(rbase + reg) * SA_D + col] = __float2bfloat16(acc[1][mi][reg] + bvk);
        }
        union { __hip_bfloat16 hh[4]; short4 s4; } u;
#pragma unroll
        for (int reg = 0; reg < 4; ++reg)
            u.hh[reg] = __float2bfloat16(acc[2][mi][reg] + bvv);
        *reinterpret_cast<short4*>(&VtT[(size_t)col * SA_N + rbase]) = u.s4;
    }
}

// ---------------- bf16 MFMA GEMM 64x64 (R8 body, LDS-staged A and B) ----------------
__global__ __launch_bounds__(256) void gemm_out_kernel(
    const __hip_bfloat16* __restrict__ A, const __hip_bfloat16* __restrict__ Bt,
    const float* __restrict__ bias, float* __restrict__ Cout)
{
    __shared__ __align__(16) char As[64 * 128];
    __shared__ __align__(16) char Bs[64 * 128];
    const int tid = threadIdx.x;
    const int wave = tid >> 6, lane = tid & 63;
    const int m = lane & 15, quad = lane >> 4;
    const int wm = wave >> 1, wn = wave & 1;
    const int row0 = blockIdx.y * 64, col0 = blockIdx.x * 64;

    f32x4 acc[2][2];
#pragma unroll
    for (int i = 0; i < 2; ++i)
#pragma unroll
        for (int j = 0; j < 2; ++j) acc[i][j] = (f32x4){0.f, 0.f, 0.f, 0.f};

    const int sr = tid >> 3;
    const int sc = tid & 7;

    for (int k0 = 0; k0 < SA_D; k0 += 64) {
#pragma unroll
        for (int p = 0; p < 2; ++p) {
            const int r = p * 32 + sr;
            const int pc = (sc ^ (r & 7)) * 16;
            const char* ga = (const char*)(A + (size_t)(row0 + r) * SA_D + k0) + pc;
            __builtin_amdgcn_global_load_lds((gmem_t*)ga,
                (lds_t*)(As + p * 4096 + wave * 1024), 16, 0, 0);
            const char* gb = (const char*)(Bt + (size_t)(col0 + r) * SA_D + k0) + pc;
            __builtin_amdgcn_global_load_lds((gmem_t*)gb,
                (lds_t*)(Bs + p * 4096 + wave * 1024), 16, 0, 0);
        }
        __syncthreads();

#pragma unroll
        for (int s = 0; s < 2; ++s) {
            bf16x8 af[2], bfr[2];
#pragma unroll
            for (int mi = 0; mi < 2; ++mi) {
                const int row = wm * 32 + mi * 16 + m;
                const int pc = (s * 4 + quad) ^ (row & 7);
                af[mi] = *reinterpret_cast<const bf16x8*>(As + row * 128 + pc * 16);
            }
#pragma unroll
            for (int ni = 0; ni < 2; ++ni) {
                const int col = wn * 32 + ni * 16 + m;
                const int pc = (s * 4 + quad) ^ (col & 7);
                bfr[ni] = *reinterpret_cast<const bf16x8*>(Bs + col * 128 + pc * 16);
            }
#pragma unroll
            for (int mi = 0; mi < 2; ++mi)
#pragma unroll
                for (int ni = 0; ni < 2; ++ni)
                    acc[mi][ni] = __builtin_amdgcn_mfma_f32_16x16x32_bf16(
                        af[mi], bfr[ni], acc[mi][ni], 0, 0, 0);
        }
        __syncthreads();
    }

#pragma unroll
    for (int ni = 0; ni < 2; ++ni) {
        const int col = col0 + wn * 32 + ni * 16 + m;
        const float bv = bias[col];
#pragma unroll
        for (int mi = 0; mi < 2; ++mi) {
            const int rbase = row0 + wm * 32 + mi * 16 + quad * 4;
#pragma unroll
            for (int reg = 0; reg < 4; ++reg)
                Cout[(size_t)(rbase + reg) * SA_D + col] = acc[mi][ni][reg] + bv;
        }
    }
}

// ---------------- MFMA flash attention v4 (exact R8: best measured) ----------------
__global__ __launch_bounds__(512, 4) void flash_mfma_kernel(
    const __hip_bfloat16* __restrict__ Qb,  // [N][D], pre-scaled by SC2
    const __hip_bfloat16* __restrict__ Kb,  // [N][D]
    const __hip_bfloat16* __restrict__ Vt,  // [D][N]
    __hip_bfloat16* __restrict__ O)         // [N][D]
{
    const int b = blockIdx.x;
    const int h = b & 15;
    const int qraw = b >> 4;
    const int qt = (qraw < 16) ? qraw : 47 - qraw;  // fold for CU balance
    const int row0 = qt * 64;
    const int ntiles = (qt >> 1) + 1;               // 128-key tiles

    const int tid = threadIdx.x;
    const int wave = tid >> 6, lane = tid & 63;
    const int g = wave >> 2, w4 = wave & 3;         // group, wave-in-group
    const int ln = lane & 15, quad = lane >> 4;

    __shared__ __align__(16) char Qs[64 * 128];     // [qrow][dim] bf16
    __shared__ __align__(16) char Ks[128 * 128];    // [key][dim] bf16 (reused as merge buf)
    __shared__ __align__(16) char Vs[64 * 256];     // [dim][key] bf16, 128 keys/row
    __shared__ __align__(16) char Ps[2][64 * 144];  // per-group [qrow][key] bf16
    __shared__ float lmerge[64];

    // stage Q tile once: 64 rows x 8 chunks = 512 loads, 1 round
    {
        const int r = wave * 8 + (lane >> 3);
        const int pc = ((lane & 7) ^ (r & 7)) * 16;
        const char* gq = (const char*)(Qb + (size_t)(row0 + r) * SA_D + h * SA_HD) + pc;
        __builtin_amdgcn_global_load_lds((gmem_t*)gq,
            (lds_t*)(Qs + wave * 1024), 16, 0, 0);
    }

    f32x4 oacc[4], lacc;
#pragma unroll
    for (int dg = 0; dg < 4; ++dg) oacc[dg] = (f32x4){0.f, 0.f, 0.f, 0.f};
    lacc = (f32x4){0.f, 0.f, 0.f, 0.f};

    const short one_bf = (short)0x3F80;
    const bf16x8 ones = {one_bf, one_bf, one_bf, one_bf, one_bf, one_bf, one_bf, one_bf};

    for (int kt = 0; kt < ntiles; ++kt) {
        __syncthreads();
#pragma unroll
        for (int p = 0; p < 2; ++p) {
            const int r = p * 64 + wave * 8 + (lane >> 3);
            const int pc = ((lane & 7) ^ (r & 7)) * 16;
            const char* gk = (const char*)(Kb + (size_t)(kt * 128 + r) * SA_D + h * SA_HD) + pc;
            __builtin_amdgcn_global_load_lds((gmem_t*)gk,
                (lds_t*)(Ks + p * 8192 + wave * 1024), 16, 0, 0);
        }
#pragma unroll
        for (int p = 0; p < 2; ++p) {
            const int r = p * 32 + wave * 4 + (lane >> 4);
            const int pc = ((lane & 15) ^ (r & 15)) * 16;
            const char* gv = (const char*)(Vt + (size_t)(h * SA_HD + r) * SA_N + kt * 128) + pc;
            __builtin_amdgcn_global_load_lds((gmem_t*)gv,
                (lds_t*)(Vs + p * 8192 + wave * 1024), 16, 0, 0);
        }
        __syncthreads();

        // S = Q K^T : wave's 16 q-rows x group's 64 keys
        f32x4 sacc[4];
#pragma unroll
        for (int gg = 0; gg < 4; ++gg) sacc[gg] = (f32x4){0.f, 0.f, 0.f, 0.f};
        const int mrow = w4 * 16 + ln;
#pragma unroll
        for (int s = 0; s < 2; ++s) {
            const int pca = (s * 4 + quad) ^ (mrow & 7);
            bf16x8 af = *reinterpret_cast<const bf16x8*>(Qs + mrow * 128 + pca * 16);
#pragma unroll
            for (int gg = 0; gg < 4; ++gg) {
                const int krow = g * 64 + gg * 16 + ln;
                const int pcb = (s * 4 + quad) ^ (krow & 7);
                bf16x8 bf = *reinterpret_cast<const bf16x8*>(Ks + krow * 128 + pcb * 16);
                sacc[gg] = __builtin_amdgcn_mfma_f32_16x16x32_bf16(af, bf, sacc[gg], 0, 0, 0);
            }
        }

        // P = exp2(S) + causal mask (only last tile straddles diagonal)
        const bool last = (kt == ntiles - 1);
        const int prow_b = w4 * 16 + quad * 4;
        const int qrow_b = row0 + prow_b;
        char* Pg = Ps[g];
#pragma unroll
        for (int gg = 0; gg < 4; ++gg) {
            const int key = kt * 128 + g * 64 + gg * 16 + ln;
#pragma unroll
            for (int reg = 0; reg < 4; ++reg) {
                float p = exp2f(sacc[gg][reg]);
                if (last && key > (qrow_b + reg)) p = 0.f;
                *reinterpret_cast<__hip_bfloat16*>(
                    Pg + (prow_b + reg) * 144 + (gg * 16 + ln) * 2) = __float2bfloat16(p);
            }
        }

        // O += P V ; l += P . ones
#pragma unroll
        for (int s2 = 0; s2 < 2; ++s2) {
            bf16x8 pf = *reinterpret_cast<const bf16x8*>(
                Pg + (w4 * 16 + ln) * 144 + s2 * 64 + quad * 16);
            lacc = __builtin_amdgcn_mfma_f32_16x16x32_bf16(pf, ones, lacc, 0, 0, 0);
#pragma unroll
            for (int dg = 0; dg < 4; ++dg) {
                const int vrow = dg * 16 + ln;
                const int kc = g * 8 + s2 * 4 + quad;
                const int pcb = (kc ^ (vrow & 15)) * 16;
                bf16x8 vf = *reinterpret_cast<const bf16x8*>(Vs + vrow * 256 + pcb);
                oacc[dg] = __builtin_amdgcn_mfma_f32_16x16x32_bf16(pf, vf, oacc[dg], 0, 0, 0);
            }
        }
    }

    // merge groups: group 1 dumps fp32 partials into Ks (16 KB = 64x64 f32)
    __syncthreads();
    float* Kf = reinterpret_cast<float*>(Ks);
    if (g == 1) {
#pragma unroll
        for (int reg = 0; reg < 4; ++reg) {
            const int row = w4 * 16 + quad * 4 + reg;
#pragma unroll
            for (int dg = 0; dg < 4; ++dg)
                Kf[row * 64 + dg * 16 + ln] = oacc[dg][reg];
            if (ln == 0) lmerge[row] = lacc[reg];
        }
    }
    __syncthreads();
    if (g == 0) {
#pragma unroll
        for (int reg = 0; reg < 4; ++reg) {
            const int row = w4 * 16 + quad * 4 + reg;
            const float inv = 1.0f / (lacc[reg] + lmerge[row]);
            const int qrow = row0 + row;
#pragma unroll
            for (int dg = 0; dg < 4; ++dg)
                O[(size_t)qrow * SA_D + h * SA_HD + dg * 16 + ln] =
                    __float2bfloat16((oacc[dg][reg] + Kf[row * 64 + dg * 16 + ln]) * inv);
        }
    }
}

extern "C" void kernel_launch(void* const* d_in, const int* in_sizes, int n_in,
                              void* d_out, int out_size, void* d_ws, size_t ws_size,
                              hipStream_t stream) {
    const float* x  = (const float*)d_in[0];
    const float* Wq = (const float*)d_in[1];
    const float* bq = (const float*)d_in[2];
    const float* Wk = (const float*)d_in[3];
    const float* bk = (const float*)d_in[4];
    const float* Wv = (const float*)d_in[5];
    const float* bv = (const float*)d_in[6];
    const float* Wo = (const float*)d_in[7];
    const float* bo = (const float*)d_in[8];
    float* out = (float*)d_out;

    const size_t ND = (size_t)SA_N * SA_D;
    const size_t DD = (size_t)SA_D * SA_D;
    __hip_bfloat16* xbf   = (__hip_bfloat16*)d_ws;
    __hip_bfloat16* WtAll = xbf + ND;
    __hip_bfloat16* Qb    = WtAll + 4 * DD;
    __hip_bfloat16* Kb    = Qb + ND;
    __hip_bfloat16* VtT   = Kb + ND;
    __hip_bfloat16* Abf   = VtT + ND;

    prep_kernel<<<dim3(32, 32, 6), 256, 0, stream>>>(x, Wq, Wk, Wv, Wo, xbf, WtAll);
    gemm_qkv_kernel<<<dim3(SA_D / 32, SA_N / 64), 256, 0, stream>>>(
        xbf, WtAll, bq, bk, bv, Qb, Kb, VtT);
    flash_mfma_kernel<<<dim3(512), 512, 0, stream>>>(Qb, Kb, VtT, Abf);
    gemm_out_kernel<<<dim3(SA_D / 64, SA_N / 64), 256, 0, stream>>>(
        Abf, WtAll + 3 * DD, bo, out);
}

// Round 12
// 141.938 us; speedup vs baseline: 1.2932x; 1.0151x over previous
//
#include <hip/hip_runtime.h>
#include <hip/hip_bf16.h>
#include <math.h>

#define SA_N 2048
#define SA_D 1024
#define SA_H 16
#define SA_HD 64

typedef __attribute__((ext_vector_type(8))) short bf16x8;
typedef __attribute__((ext_vector_type(4))) float f32x4;
typedef __attribute__((address_space(3))) void lds_t;
typedef __attribute__((address_space(1))) void gmem_t;

#define SC2 0.18033688011112042f   // (1/sqrt(64)) * log2(e), folded into Wq/bq

// ---------------- merged prep: x->bf16 and 4x W[K][N] -> bf16 Wt[N][K] ----------------
__global__ __launch_bounds__(256) void prep_kernel(
    const float* __restrict__ x,
    const float* __restrict__ Wq, const float* __restrict__ Wk,
    const float* __restrict__ Wv, const float* __restrict__ Wo,
    __hip_bfloat16* __restrict__ xbf, __hip_bfloat16* __restrict__ WtAll)
{
    const int tid = threadIdx.x;
    const int z = blockIdx.z;
    if (z < 2) {
        const int r = z * 1024 + blockIdx.y * 32 + (tid >> 3);
        const int c = blockIdx.x * 32 + (tid & 7) * 4;
        const size_t idx = (size_t)r * SA_D + c;
        float4 v = *reinterpret_cast<const float4*>(&x[idx]);
        union { __hip_bfloat16 hh[4]; short4 s4; } u;
        u.hh[0] = __float2bfloat16(v.x);
        u.hh[1] = __float2bfloat16(v.y);
        u.hh[2] = __float2bfloat16(v.z);
        u.hh[3] = __float2bfloat16(v.w);
        *reinterpret_cast<short4*>(&xbf[idx]) = u.s4;
    } else {
        const int w = z - 2;
        const float* W = (w == 0) ? Wq : (w == 1) ? Wk : (w == 2) ? Wv : Wo;
        const float scale = (w == 0) ? SC2 : 1.0f;
        __hip_bfloat16* Wt = WtAll + (size_t)w * SA_D * SA_D;
        __shared__ float t[32][33];
        const int c0 = blockIdx.x * 32, r0 = blockIdx.y * 32;
        const int tx = tid & 31, ty = tid >> 5;
#pragma unroll
        for (int p = 0; p < 4; ++p)
            t[ty + p * 8][tx] = W[(size_t)(r0 + ty + p * 8) * SA_D + c0 + tx] * scale;
        __syncthreads();
#pragma unroll
        for (int p = 0; p < 4; ++p)
            Wt[(size_t)(c0 + ty + p * 8) * SA_D + r0 + tx] =
                __float2bfloat16(t[tx][ty + p * 8]);
    }
}

// ---------------- fused QKV GEMM (R11) + permuted-key V output ----------------
// V is written in PERMUTED key order: within each 64-key block,
// key K -> pos (K%16)*4 + (K%64)/16. This makes the flash kernel's P-store
// vectorizable (ds_write_b64) while keeping V staging/fragment reads contiguous.
__global__ __launch_bounds__(256) void gemm_qkv_kernel(
    const __hip_bfloat16* __restrict__ xbf, const __hip_bfloat16* __restrict__ WtAll,
    const float* __restrict__ bq, const float* __restrict__ bk, const float* __restrict__ bv,
    __hip_bfloat16* __restrict__ Qb, __hip_bfloat16* __restrict__ Kb,
    __hip_bfloat16* __restrict__ VtT)
{
    __shared__ __align__(16) char As[64 * 128];
    __shared__ __align__(16) char Bs[3][32 * 128];

    const int tid = threadIdx.x;
    const int wave = tid >> 6, lane = tid & 63;
    const int m = lane & 15, quad = lane >> 4;
    const int wm = wave >> 1, wn = wave & 1;
    const int row0 = blockIdx.y * 64, col0 = blockIdx.x * 32;

    f32x4 acc[3][2];
#pragma unroll
    for (int w = 0; w < 3; ++w)
#pragma unroll
        for (int mi = 0; mi < 2; ++mi) acc[w][mi] = (f32x4){0.f, 0.f, 0.f, 0.f};

    const int sr = tid >> 3;   // 0..31
    const int sc = tid & 7;    // chunk

    for (int k0 = 0; k0 < SA_D; k0 += 64) {
#pragma unroll
        for (int p = 0; p < 2; ++p) {
            const int r = p * 32 + sr;
            const int pc = (sc ^ (r & 7)) * 16;
            const char* ga = (const char*)(xbf + (size_t)(row0 + r) * SA_D + k0) + pc;
            __builtin_amdgcn_global_load_lds((gmem_t*)ga,
                (lds_t*)(As + p * 4096 + wave * 1024), 16, 0, 0);
        }
#pragma unroll
        for (int w = 0; w < 3; ++w) {
            const int pc = (sc ^ (sr & 7)) * 16;
            const char* gb = (const char*)(WtAll + (size_t)w * SA_D * SA_D
                                           + (size_t)(col0 + sr) * SA_D + k0) + pc;
            __builtin_amdgcn_global_load_lds((gmem_t*)gb,
                (lds_t*)(Bs[w] + wave * 1024), 16, 0, 0);
        }
        __syncthreads();

#pragma unroll
        for (int s = 0; s < 2; ++s) {
            bf16x8 af[2];
#pragma unroll
            for (int mi = 0; mi < 2; ++mi) {
                const int row = wm * 32 + mi * 16 + m;
                const int pc = (s * 4 + quad) ^ (row & 7);
                af[mi] = *reinterpret_cast<const bf16x8*>(As + row * 128 + pc * 16);
            }
            const int rb = wn * 16 + m;
            const int pcb = (s * 4 + quad) ^ (rb & 7);
#pragma unroll
            for (int w = 0; w < 3; ++w) {
                bf16x8 bf = *reinterpret_cast<const bf16x8*>(Bs[w] + rb * 128 + pcb * 16);
#pragma unroll
                for (int mi = 0; mi < 2; ++mi)
                    acc[w][mi] = __builtin_amdgcn_mfma_f32_16x16x32_bf16(
                        af[mi], bf, acc[w][mi], 0, 0, 0);
            }
        }
        __syncthreads();
    }

    // epilogue: Q,K natural bf16; V transposed [N][M] bf16 with permuted key order
    const int col = col0 + wn * 16 + m;
    const float bvq = bq[col] * SC2, bvk = bk[col], bvv = bv[col];
#pragma unroll
    for (int mi = 0; mi < 2; ++mi) {
        const int rbase = row0 + wm * 32 + mi * 16 + quad * 4;
#pragma unroll
        for (int reg = 0; reg < 4; ++reg) {
            Qb[(size_t)(rbase + reg) * SA_D + col] = __float2bfloat16(acc[0][mi][reg] + bvq);
            Kb[(size_t)(rbase + reg) * SA_D + col] = __float2bfloat16(acc[1][mi][reg] + bvk);
        }
        // permuted V store: key K=rbase+reg -> row0 + (quad*4+reg)*4 + (wm*2+mi)
#pragma unroll
        for (int reg = 0; reg < 4; ++reg) {
            const int jp = (quad * 4 + reg) * 4 + (wm * 2 + mi);
            VtT[(size_t)col * SA_N + row0 + jp] = __float2bfloat16(acc[2][mi][reg] + bvv);
        }
    }
}

// ---------------- bf16 MFMA GEMM 64x64 (R11 out-proj, unchanged) ----------------
__global__ __launch_bounds__(256) void gemm_out_kernel(
    const __hip_bfloat16* __restrict__ A, const __hip_bfloat16* __restrict__ Bt,
    const float* __restrict__ bias, float* __restrict__ Cout)
{
    __shared__ __align__(16) char As[64 * 128];
    __shared__ __align__(16) char Bs[64 * 128];
    const int tid = threadIdx.x;
    const int wave = tid >> 6, lane = tid & 63;
    const int m = lane & 15, quad = lane >> 4;
    const int wm = wave >> 1, wn = wave & 1;
    const int row0 = blockIdx.y * 64, col0 = blockIdx.x * 64;

    f32x4 acc[2][2];
#pragma unroll
    for (int i = 0; i < 2; ++i)
#pragma unroll
        for (int j = 0; j < 2; ++j) acc[i][j] = (f32x4){0.f, 0.f, 0.f, 0.f};

    const int sr = tid >> 3;
    const int sc = tid & 7;

    for (int k0 = 0; k0 < SA_D; k0 += 64) {
#pragma unroll
        for (int p = 0; p < 2; ++p) {
            const int r = p * 32 + sr;
            const int pc = (sc ^ (r & 7)) * 16;
            const char* ga = (const char*)(A + (size_t)(row0 + r) * SA_D + k0) + pc;
            __builtin_amdgcn_global_load_lds((gmem_t*)ga,
                (lds_t*)(As + p * 4096 + wave * 1024), 16, 0, 0);
            const char* gb = (const char*)(Bt + (size_t)(col0 + r) * SA_D + k0) + pc;
            __builtin_amdgcn_global_load_lds((gmem_t*)gb,
                (lds_t*)(Bs + p * 4096 + wave * 1024), 16, 0, 0);
        }
        __syncthreads();

#pragma unroll
        for (int s = 0; s < 2; ++s) {
            bf16x8 af[2], bfr[2];
#pragma unroll
            for (int mi = 0; mi < 2; ++mi) {
                const int row = wm * 32 + mi * 16 + m;
                const int pc = (s * 4 + quad) ^ (row & 7);
                af[mi] = *reinterpret_cast<const bf16x8*>(As + row * 128 + pc * 16);
            }
#pragma unroll
            for (int ni = 0; ni < 2; ++ni) {
                const int col = wn * 32 + ni * 16 + m;
                const int pc = (s * 4 + quad) ^ (col & 7);
                bfr[ni] = *reinterpret_cast<const bf16x8*>(Bs + col * 128 + pc * 16);
            }
#pragma unroll
            for (int mi = 0; mi < 2; ++mi)
#pragma unroll
                for (int ni = 0; ni < 2; ++ni)
                    acc[mi][ni] = __builtin_amdgcn_mfma_f32_16x16x32_bf16(
                        af[mi], bfr[ni], acc[mi][ni], 0, 0, 0);
        }
        __syncthreads();
    }

#pragma unroll
    for (int ni = 0; ni < 2; ++ni) {
        const int col = col0 + wn * 32 + ni * 16 + m;
        const float bv = bias[col];
#pragma unroll
        for (int mi = 0; mi < 2; ++mi) {
            const int rbase = row0 + wm * 32 + mi * 16 + quad * 4;
#pragma unroll
            for (int reg = 0; reg < 4; ++reg)
                Cout[(size_t)(rbase + reg) * SA_D + col] = acc[mi][ni][reg] + bv;
        }
    }
}

// ---------------- MFMA flash attention v6: split-K groups + packed P-store ----------------
// R8/R11 v4 structure; P now stored with permuted key order k' = ln*4 + gg
// (within each group's 64 keys), so each lane's 4 values per output row are
// CONTIGUOUS -> 4x ds_write_b64 replaces 16x ds_write_b16. V arrives already
// permuted from gemm_qkv; PV fragment reads are unchanged (contiguous b128).
__global__ __launch_bounds__(512, 4) void flash_mfma_kernel(
    const __hip_bfloat16* __restrict__ Qb,  // [N][D], pre-scaled by SC2
    const __hip_bfloat16* __restrict__ Kb,  // [N][D]
    const __hip_bfloat16* __restrict__ Vt,  // [D][N], keys permuted per 64-block
    __hip_bfloat16* __restrict__ O)         // [N][D]
{
    const int b = blockIdx.x;
    const int h = b & 15;
    const int qraw = b >> 4;
    const int qt = (qraw < 16) ? qraw : 47 - qraw;  // fold for CU balance
    const int row0 = qt * 64;
    const int ntiles = (qt >> 1) + 1;               // 128-key tiles

    const int tid = threadIdx.x;
    const int wave = tid >> 6, lane = tid & 63;
    const int g = wave >> 2, w4 = wave & 3;         // group, wave-in-group
    const int ln = lane & 15, quad = lane >> 4;

    __shared__ __align__(16) char Qs[64 * 128];     // [qrow][dim] bf16
    __shared__ __align__(16) char Ks[128 * 128];    // [key][dim] bf16 (reused as merge buf)
    __shared__ __align__(16) char Vs[64 * 256];     // [dim][key'] bf16, 128 keys/row
    __shared__ __align__(16) char Ps[2][64 * 144];  // per-group [qrow][key'] bf16
    __shared__ float lmerge[64];

    // stage Q tile once
    {
        const int r = wave * 8 + (lane >> 3);
        const int pc = ((lane & 7) ^ (r & 7)) * 16;
        const char* gq = (const char*)(Qb + (size_t)(row0 + r) * SA_D + h * SA_HD) + pc;
        __builtin_amdgcn_global_load_lds((gmem_t*)gq,
            (lds_t*)(Qs + wave * 1024), 16, 0, 0);
    }

    f32x4 oacc[4], lacc;
#pragma unroll
    for (int dg = 0; dg < 4; ++dg) oacc[dg] = (f32x4){0.f, 0.f, 0.f, 0.f};
    lacc = (f32x4){0.f, 0.f, 0.f, 0.f};

    const short one_bf = (short)0x3F80;
    const bf16x8 ones = {one_bf, one_bf, one_bf, one_bf, one_bf, one_bf, one_bf, one_bf};

    for (int kt = 0; kt < ntiles; ++kt) {
        __syncthreads();
#pragma unroll
        for (int p = 0; p < 2; ++p) {
            const int r = p * 64 + wave * 8 + (lane >> 3);
            const int pc = ((lane & 7) ^ (r & 7)) * 16;
            const char* gk = (const char*)(Kb + (size_t)(kt * 128 + r) * SA_D + h * SA_HD) + pc;
            __builtin_amdgcn_global_load_lds((gmem_t*)gk,
                (lds_t*)(Ks + p * 8192 + wave * 1024), 16, 0, 0);
        }
#pragma unroll
        for (int p = 0; p < 2; ++p) {
            const int r = p * 32 + wave * 4 + (lane >> 4);
            const int pc = ((lane & 15) ^ (r & 15)) * 16;
            const char* gv = (const char*)(Vt + (size_t)(h * SA_HD + r) * SA_N + kt * 128) + pc;
            __builtin_amdgcn_global_load_lds((gmem_t*)gv,
                (lds_t*)(Vs + p * 8192 + wave * 1024), 16, 0, 0);
        }
        __syncthreads();

        // S = Q K^T : wave's 16 q-rows x group's 64 keys
        f32x4 sacc[4];
#pragma unroll
        for (int gg = 0; gg < 4; ++gg) sacc[gg] = (f32x4){0.f, 0.f, 0.f, 0.f};
        const int mrow = w4 * 16 + ln;
#pragma unroll
        for (int s = 0; s < 2; ++s) {
            const int pca = (s * 4 + quad) ^ (mrow & 7);
            bf16x8 af = *reinterpret_cast<const bf16x8*>(Qs + mrow * 128 + pca * 16);
#pragma unroll
            for (int gg = 0; gg < 4; ++gg) {
                const int krow = g * 64 + gg * 16 + ln;
                const int pcb = (s * 4 + quad) ^ (krow & 7);
                bf16x8 bf = *reinterpret_cast<const bf16x8*>(Ks + krow * 128 + pcb * 16);
                sacc[gg] = __builtin_amdgcn_mfma_f32_16x16x32_bf16(af, bf, sacc[gg], 0, 0, 0);
            }
        }

        // P = exp2(S) + causal mask; packed b64 store per row (permuted keys)
        const bool last = (kt == ntiles - 1);
        const int prow_b = w4 * 16 + quad * 4;
        const int qrow_b = row0 + prow_b;
        char* Pg = Ps[g];
#pragma unroll
        for (int reg = 0; reg < 4; ++reg) {
            union { __hip_bfloat16 hh[4]; short4 s4; } u;
#pragma unroll
            for (int gg = 0; gg < 4; ++gg) {
                const int key = kt * 128 + g * 64 + gg * 16 + ln;
                float p = exp2f(sacc[gg][reg]);
                if (last && key > (qrow_b + reg)) p = 0.f;
                u.hh[gg] = __float2bfloat16(p);
            }
            *reinterpret_cast<short4*>(Pg + (prow_b + reg) * 144 + ln * 8) = u.s4;
        }

        // O += P V ; l += P . ones   (k' order consistent between P and Vs)
#pragma unroll
        for (int s2 = 0; s2 < 2; ++s2) {
            bf16x8 pf = *reinterpret_cast<const bf16x8*>(
                Pg + (w4 * 16 + ln) * 144 + s2 * 64 + quad * 16);
            lacc = __builtin_amdgcn_mfma_f32_16x16x32_bf16(pf, ones, lacc, 0, 0, 0);
#pragma unroll
            for (int dg = 0; dg < 4; ++dg) {
                const int vrow = dg * 16 + ln;
                const int kc = g * 8 + s2 * 4 + quad;
                const int pcb = (kc ^ (vrow & 15)) * 16;
                bf16x8 vf = *reinterpret_cast<const bf16x8*>(Vs + vrow * 256 + pcb);
                oacc[dg] = __builtin_amdgcn_mfma_f32_16x16x32_bf16(pf, vf, oacc[dg], 0, 0, 0);
            }
        }
    }

    // merge groups: group 1 dumps fp32 partials into Ks (16 KB = 64x64 f32)
    __syncthreads();
    float* Kf = reinterpret_cast<float*>(Ks);
    if (g == 1) {
#pragma unroll
        for (int reg = 0; reg < 4; ++reg) {
            const int row = w4 * 16 + quad * 4 + reg;
#pragma unroll
            for (int dg = 0; dg < 4; ++dg)
                Kf[row * 64 + dg * 16 + ln] = oacc[dg][reg];
            if (ln == 0) lmerge[row] = lacc[reg];
        }
    }
    __syncthreads();
    if (g == 0) {
#pragma unroll
        for (int reg = 0; reg < 4; ++reg) {
            const int row = w4 * 16 + quad * 4 + reg;
            const float inv = 1.0f / (lacc[reg] + lmerge[row]);
            const int qrow = row0 + row;
#pragma unroll
            for (int dg = 0; dg < 4; ++dg)
                O[(size_t)qrow * SA_D + h * SA_HD + dg * 16 + ln] =
                    __float2bfloat16((oacc[dg][reg] + Kf[row * 64 + dg * 16 + ln]) * inv);
        }
    }
}

extern "C" void kernel_launch(void* const* d_in, const int* in_sizes, int n_in,
                              void* d_out, int out_size, void* d_ws, size_t ws_size,
                              hipStream_t stream) {
    const float* x  = (const float*)d_in[0];
    const float* Wq = (const float*)d_in[1];
    const float* bq = (const float*)d_in[2];
    const float* Wk = (const float*)d_in[3];
    const float* bk = (const float*)d_in[4];
    const float* Wv = (const float*)d_in[5];
    const float* bv = (const float*)d_in[6];
    const float* Wo = (const float*)d_in[7];
    const float* bo = (const float*)d_in[8];
    float* out = (float*)d_out;

    const size_t ND = (size_t)SA_N * SA_D;
    const size_t DD = (size_t)SA_D * SA_D;
    __hip_bfloat16* xbf   = (__hip_bfloat16*)d_ws;
    __hip_bfloat16* WtAll = xbf + ND;
    __hip_bfloat16* Qb    = WtAll + 4 * DD;
    __hip_bfloat16* Kb    = Qb + ND;
    __hip_bfloat16* VtT   = Kb + ND;
    __hip_bfloat16* Abf   = VtT + ND;

    prep_kernel<<<dim3(32, 32, 6), 256, 0, stream>>>(x, Wq, Wk, Wv, Wo, xbf, WtAll);
    gemm_qkv_kernel<<<dim3(SA_D / 32, SA_N / 64), 256, 0, stream>>>(
        xbf, WtAll, bq, bk, bv, Qb, Kb, VtT);
    flash_mfma_kernel<<<dim3(512), 512, 0, stream>>>(Qb, Kb, VtT, Abf);
    gemm_out_kernel<<<dim3(SA_D / 64, SA_N / 64), 256, 0, stream>>>(
        Abf, WtAll + 3 * DD, bo, out);
}